// Round 4
// baseline (1558.730 us; speedup 1.0000x reference)
//
#include <hip/hip_runtime.h>

typedef unsigned int u32;
typedef unsigned short u16;
typedef __attribute__((ext_vector_type(8))) short bf16x8;
typedef __attribute__((ext_vector_type(4))) float f32x4;

#define DEVI static __device__ __forceinline__

DEVI u16 f2bf(float f) {
    u32 u = __float_as_uint(f);
    u32 r = u + 0x7FFFu + ((u >> 16) & 1u);   // RNE (inputs finite)
    return (u16)(r >> 16);
}
DEVI float bf2f(u16 s) { return __uint_as_float(((u32)s) << 16); }
DEVI void split2(float a, u16& h, u16& l) {   // a ≈ hi + lo, residual ≤ 2^-18|a|
    h = f2bf(a);
    l = f2bf(a - bf2f(h));
}

union U4 { uint4 v; u16 s[8]; };

// ---------------------------------------------------------------- f32 -> (hi,lo) bf16 planes
__global__ __launch_bounds__(256) void convert_split_kernel(const float* __restrict__ in,
                                                            u16* __restrict__ hi,
                                                            u16* __restrict__ lo, int n) {
    int i = blockIdx.x * 256 + threadIdx.x;
    if (i < n) { u16 h, l; split2(in[i], h, l); hi[i] = h; lo[i] = l; }
}

// ---------------------------------------------------------------- proxy-side K/V (tiny, fp32 VALU)
struct KVArgs {
    const float *proxy;
    const float *ow1, *og1, *ob1, *om1, *ov1;
    const float *ow2, *og2, *ob2, *om2, *ov2;
    const float *dw,  *dg,  *db,  *dm,  *dv;
    float *kmat;   // [B][256][19]  (channel-major)
    float *vmat;   // [B][19][256]
};
__global__ __launch_bounds__(256) void kv_kernel(KVArgs a) {
    __shared__ float pl[512 * 19];
    __shared__ float t1[256 * 19];
    const int t = threadIdx.x;
    const int b = blockIdx.x;
    const float* pb = a.proxy + (size_t)b * 512 * 19;
    for (int i = t; i < 512 * 19; i += 256) pl[i] = pb[i];
    __syncthreads();
    const int o = t;
    {
        float acc[19] = {0.f};
        const float* wr = a.ow1 + (size_t)o * 512;
        for (int c = 0; c < 512; ++c) {
            float wv = wr[c];
#pragma unroll
            for (int kk = 0; kk < 19; ++kk) acc[kk] += wv * pl[c * 19 + kk];
        }
        float sc = a.og1[o] * __frsqrt_rn(a.ov1[o] + 1e-5f);
        float sh = a.ob1[o] - a.om1[o] * sc;
#pragma unroll
        for (int kk = 0; kk < 19; ++kk) t1[o * 19 + kk] = fmaxf(acc[kk] * sc + sh, 0.f);
    }
    __syncthreads();
    {
        float acc[19] = {0.f};
        const float* wr = a.ow2 + (size_t)o * 256;
        for (int c = 0; c < 256; ++c) {
            float wv = wr[c];
#pragma unroll
            for (int kk = 0; kk < 19; ++kk) acc[kk] += wv * t1[c * 19 + kk];
        }
        float sc = a.og2[o] * __frsqrt_rn(a.ov2[o] + 1e-5f);
        float sh = a.ob2[o] - a.om2[o] * sc;
#pragma unroll
        for (int kk = 0; kk < 19; ++kk)
            a.kmat[((size_t)b * 256 + o) * 19 + kk] = fmaxf(acc[kk] * sc + sh, 0.f);
    }
    {
        float acc[19] = {0.f};
        const float* wr = a.dw + (size_t)o * 512;
        for (int c = 0; c < 512; ++c) {
            float wv = wr[c];
#pragma unroll
            for (int kk = 0; kk < 19; ++kk) acc[kk] += wv * pl[c * 19 + kk];
        }
        float sc = a.dg[o] * __frsqrt_rn(a.dv[o] + 1e-5f);
        float sh = a.db[o] - a.dm[o] * sc;
#pragma unroll
        for (int kk = 0; kk < 19; ++kk)
            a.vmat[((size_t)b * 19 + kk) * 256 + o] = fmaxf(acc[kk] * sc + sh, 0.f);
    }
}

// ---------------------------------------------------------------- attention
// q2t: [256][chunk] fp32 (transposed, pass-local). Block = 64 pixels, 4 c-quarter waves.
// All global accesses coalesced; ctx stores staged through LDS -> full-sector uint4.
struct AttnArgs { const float* q2t; const float* kmat; const float* vmat;
                  u16* ctxh; u16* ctxl; int chunk; long long p_off; };
__global__ __launch_bounds__(256) void attn_kernel(AttnArgs a) {
    __shared__ float vl[19 * 256];                 // [kk][c], live whole kernel (19456 B)
    __shared__ char smem[40960];                   // phase1: kl(19456)+simpart(21504); phase2: tile(33792)
    float* kl = (float*)smem;                      // [c][19]
    float* simpart = (float*)(smem + 19456);       // [4][64][21]
    u16* tile = (u16*)smem;                        // [64][264]
    const int t = threadIdx.x;
    const int p_loc0 = blockIdx.x * 64;            // pass-local pixel base
    const long long pg0 = a.p_off + p_loc0;        // global pixel base
    const int b = (int)(pg0 >> 14);                // 64 | 16384 -> no batch straddle
    for (int i = t; i < 4864; i += 256) { kl[i] = a.kmat[(size_t)b * 4864 + i];
                                          vl[i] = a.vmat[(size_t)b * 4864 + i]; }
    __syncthreads();
    const int p_l = t & 63, ks = t >> 6;
    // phase 1: partial sims over this wave's 64-channel quarter (q reads coalesced: lanes = pixels)
    float sim[19];
#pragma unroll
    for (int kk = 0; kk < 19; ++kk) sim[kk] = 0.f;
    const float* qbase = a.q2t + p_loc0 + p_l;
    for (int j = 0; j < 64; ++j) {
        int c = ks * 64 + j;
        float qv = qbase[(size_t)c * a.chunk];
#pragma unroll
        for (int kk = 0; kk < 19; ++kk) sim[kk] += qv * kl[c * 19 + kk];  // LDS broadcast
    }
#pragma unroll
    for (int kk = 0; kk < 19; ++kk) simpart[(ks * 64 + p_l) * 21 + kk] = sim[kk];
    __syncthreads();
    // reduce + softmax (each wave redundantly computes its pixel's weights)
    float w[19];
    float mx = -1e30f;
#pragma unroll
    for (int kk = 0; kk < 19; ++kk) {
        float s = simpart[p_l * 21 + kk] + simpart[(64 + p_l) * 21 + kk]
                + simpart[(128 + p_l) * 21 + kk] + simpart[(192 + p_l) * 21 + kk];
        w[kk] = s * 0.0625f;
        mx = fmaxf(mx, w[kk]);
    }
    float ssum = 0.f;
#pragma unroll
    for (int kk = 0; kk < 19; ++kk) { w[kk] = __expf(w[kk] - mx); ssum += w[kk]; }
    const float inv = 1.f / ssum;
#pragma unroll
    for (int kk = 0; kk < 19; ++kk) w[kk] *= inv;
    __syncthreads();                               // kl/simpart dead -> tile reuse safe
    // phase 2: ctx tile per plane, staged -> coalesced stores
#pragma unroll 1
    for (int plane = 0; plane < 2; ++plane) {
#pragma unroll
        for (int g = 0; g < 8; ++g) {
            U4 tmp;
#pragma unroll
            for (int e = 0; e < 8; ++e) {
                int c = ks * 64 + g * 8 + e;
                float acc = 0.f;
#pragma unroll
                for (int kk = 0; kk < 19; ++kk) acc += w[kk] * vl[kk * 256 + c];  // broadcast
                u16 h, l; split2(acc, h, l);
                tmp.s[e] = plane ? l : h;
            }
            *reinterpret_cast<uint4*>(&tile[p_l * 264 + ks * 64 + g * 8]) = tmp.v;
        }
        __syncthreads();
        u16* C = plane ? a.ctxl : a.ctxh;
#pragma unroll
        for (int it = 0; it < 8; ++it) {
            int row = it * 8 + (t >> 5);
            int off = (t & 31) * 8;
            *reinterpret_cast<uint4*>(&C[(size_t)(pg0 + row) * 256 + off]) =
                *reinterpret_cast<const uint4*>(&tile[row * 264 + off]);
        }
        __syncthreads();
    }
}

// ---------------------------------------------------------------- split-bf16 MFMA GEMM (3-term: hh + hl + lh)
// Y[p][o] = relu(bn(A[p][:] . W[o][:])), fp32-class precision.
// ASRC 0: A = (Ah,Al) bf16 planes [131072][K] pixel-major.
// ASRC 1: A = Xf fp32 x [B][512][16384] channel-major (transpose+split fused into staging).
// MODE 0: (Yh,Yl) split planes [p][COUT], LDS-staged coalesced stores.
// MODE 1: Yf = out[b][o][16384] fp32 via LDS transpose.
// MODE 2: Yf = q2t [o][ostride] fp32 (transposed, pass-local) via LDS transpose.
template<int K, int COUT, int MODE, int ASRC>
__global__ __launch_bounds__(256, 2)
void gemm_kernel(const u16* __restrict__ Ah, const u16* __restrict__ Al,
                 const float* __restrict__ Xf,
                 const u16* __restrict__ Wh, const u16* __restrict__ Wl,
                 const float* __restrict__ gg, const float* __restrict__ bbv,
                 const float* __restrict__ mmv, const float* __restrict__ vvv,
                 u16* __restrict__ Yh, u16* __restrict__ Yl,
                 float* __restrict__ Yf, int m_off, int ostride) {
    static_assert(K % 64 == 0, "");
    constexpr int NT = K / 64;
    __shared__ u16 lds[4][128 * 64];         // planes: 0=Ah 1=Al 2=Wh 3=Wl; 64 KiB, XOR chunk-swizzled
    const int t = threadIdx.x;
    const int l = t & 63;
    const int w = t >> 6;
    const int wr = w >> 1, wc = w & 1;
    const int l15 = l & 15, l4 = l >> 4;
    const int o0 = blockIdx.x * 128;         // o fastest-varying -> A-tile L2 reuse across o-blocks
    const int m_loc = blockIdx.y * 128;
    const int m_glob = m_off + m_loc;
    const int bb = m_glob >> 14;
    const int nb = m_glob & 16383;

    f32x4 acc[4][4];
#pragma unroll
    for (int mi = 0; mi < 4; ++mi)
#pragma unroll
        for (int ni = 0; ni < 4; ++ni) acc[mi][ni] = f32x4{0.f, 0.f, 0.f, 0.f};

    uint4 rah[4], ral[4], rbh[4], rbl[4];
    float fa[4][8];

    auto stage_load = [&](int kt) {
        if constexpr (ASRC == 0) {
#pragma unroll
            for (int i = 0; i < 4; ++i) {
                int cidx = t + 256 * i, row = cidx >> 3, cg = cidx & 7;
                size_t off = (size_t)(m_glob + row) * K + kt * 64 + cg * 8;
                rah[i] = *reinterpret_cast<const uint4*>(Ah + off);
                ral[i] = *reinterpret_cast<const uint4*>(Al + off);
            }
        } else {
#pragma unroll
            for (int i = 0; i < 4; ++i) {
                int task = t + 256 * i;
                int n = task & 127, oct = task >> 7;
                const float* src = Xf + (((size_t)bb * 512 + kt * 64 + oct * 8) << 14) + nb + n;
#pragma unroll
                for (int e = 0; e < 8; ++e) fa[i][e] = src[(size_t)e << 14];
            }
        }
#pragma unroll
        for (int i = 0; i < 4; ++i) {
            int cidx = t + 256 * i, row = cidx >> 3, cg = cidx & 7;
            size_t off = (size_t)(o0 + row) * K + kt * 64 + cg * 8;
            rbh[i] = *reinterpret_cast<const uint4*>(Wh + off);
            rbl[i] = *reinterpret_cast<const uint4*>(Wl + off);
        }
    };
    auto stage_write = [&]() {
        if constexpr (ASRC == 0) {
#pragma unroll
            for (int i = 0; i < 4; ++i) {
                int cidx = t + 256 * i, row = cidx >> 3, cg = cidx & 7;
                int sc = row * 64 + ((cg ^ (row & 7)) * 8);
                *reinterpret_cast<uint4*>(&lds[0][sc]) = rah[i];
                *reinterpret_cast<uint4*>(&lds[1][sc]) = ral[i];
            }
        } else {
#pragma unroll
            for (int i = 0; i < 4; ++i) {
                int task = t + 256 * i;
                int n = task & 127, oct = task >> 7;
                U4 ph, plo;
#pragma unroll
                for (int e = 0; e < 8; ++e) split2(fa[i][e], ph.s[e], plo.s[e]);
                int sc = n * 64 + ((oct ^ (n & 7)) * 8);
                *reinterpret_cast<uint4*>(&lds[0][sc]) = ph.v;
                *reinterpret_cast<uint4*>(&lds[1][sc]) = plo.v;
            }
        }
#pragma unroll
        for (int i = 0; i < 4; ++i) {
            int cidx = t + 256 * i, row = cidx >> 3, cg = cidx & 7;
            int sc = row * 64 + ((cg ^ (row & 7)) * 8);
            *reinterpret_cast<uint4*>(&lds[2][sc]) = rbh[i];
            *reinterpret_cast<uint4*>(&lds[3][sc]) = rbl[i];
        }
    };

    stage_load(0);
    stage_write();
    __syncthreads();

    for (int kt = 0; kt < NT; ++kt) {
        const bool more = (kt + 1 < NT);
        if (more) stage_load(kt + 1);        // issue next-tile globals under MFMA
#pragma unroll
        for (int kk = 0; kk < 2; ++kk) {
            bf16x8 ah[4], al[4], bh[4], bl[4];
#pragma unroll
            for (int mi = 0; mi < 4; ++mi) {
                int row = wr * 64 + mi * 16 + l15;
                int idx = row * 64 + (((kk * 4 + l4) ^ (row & 7)) * 8);
                ah[mi] = *reinterpret_cast<const bf16x8*>(&lds[0][idx]);
                al[mi] = *reinterpret_cast<const bf16x8*>(&lds[1][idx]);
            }
#pragma unroll
            for (int ni = 0; ni < 4; ++ni) {
                int row = wc * 64 + ni * 16 + l15;
                int idx = row * 64 + (((kk * 4 + l4) ^ (row & 7)) * 8);
                bh[ni] = *reinterpret_cast<const bf16x8*>(&lds[2][idx]);
                bl[ni] = *reinterpret_cast<const bf16x8*>(&lds[3][idx]);
            }
#pragma unroll
            for (int mi = 0; mi < 4; ++mi)
#pragma unroll
                for (int ni = 0; ni < 4; ++ni) {
                    acc[mi][ni] = __builtin_amdgcn_mfma_f32_16x16x32_bf16(ah[mi], bh[ni], acc[mi][ni], 0, 0, 0);
                    acc[mi][ni] = __builtin_amdgcn_mfma_f32_16x16x32_bf16(ah[mi], bl[ni], acc[mi][ni], 0, 0, 0);
                    acc[mi][ni] = __builtin_amdgcn_mfma_f32_16x16x32_bf16(al[mi], bh[ni], acc[mi][ni], 0, 0, 0);
                }
        }
        __syncthreads();                      // all reads of buffer done
        if (more) { stage_write(); __syncthreads(); }
    }

    // hoisted BN coefficients (per ni -> this lane's o column)
    float scl[4], shf[4];
#pragma unroll
    for (int ni = 0; ni < 4; ++ni) {
        int o = o0 + wc * 64 + ni * 16 + l15;
        scl[ni] = gg[o] * __frsqrt_rn(vvv[o] + 1e-5f);
        shf[ni] = bbv[o] - mmv[o] * scl[ni];
    }

    if constexpr (MODE == 0) {
        // LDS-staged coalesced split-plane stores: tile [128][140] u16 (l4-groups hit disjoint bank octets)
        u16* tile = (u16*)&lds[0][0];
#pragma unroll 1
        for (int plane = 0; plane < 2; ++plane) {
            __syncthreads();
#pragma unroll
            for (int ni = 0; ni < 4; ++ni) {
                int o_l = wc * 64 + ni * 16 + l15;
#pragma unroll
                for (int mi = 0; mi < 4; ++mi) {
#pragma unroll
                    for (int r = 0; r < 4; ++r) {
                        int p_l = wr * 64 + mi * 16 + l4 * 4 + r;
                        float y = fmaxf(acc[mi][ni][r] * scl[ni] + shf[ni], 0.f);
                        u16 h, lo2; split2(y, h, lo2);
                        tile[p_l * 140 + o_l] = plane ? lo2 : h;
                    }
                }
            }
            __syncthreads();
            u16* Y = plane ? Yl : Yh;
#pragma unroll
            for (int it = 0; it < 8; ++it) {
                int row = it * 16 + (t >> 4);
                int off = (t & 15) * 8;
                *reinterpret_cast<uint4*>(&Y[(size_t)(m_glob + row) * COUT + o0 + off]) =
                    *reinterpret_cast<const uint4*>(&tile[row * 140 + off]);
            }
        }
    } else {
        // transpose epilogue via LDS [64][132] f32; MODE1 -> out[b][o][16384], MODE2 -> q2t[o][ostride]
        float* ldsf = reinterpret_cast<float*>(&lds[0][0]);
#pragma unroll 1
        for (int pass = 0; pass < 2; ++pass) {
            __syncthreads();
#pragma unroll
            for (int nj = 0; nj < 2; ++nj) {
                int ni = pass * 2 + nj;
                int lrow = wc * 32 + nj * 16 + l15;
                int lcolb = wr * 64 + l4 * 4;
#pragma unroll
                for (int mi = 0; mi < 4; ++mi)
#pragma unroll
                    for (int r = 0; r < 4; ++r) {
                        float y = fmaxf(acc[mi][ni][r] * scl[ni] + shf[ni], 0.f);
                        ldsf[lrow * 132 + lcolb + mi * 16 + r] = y;
                    }
            }
            __syncthreads();
#pragma unroll
            for (int j = 0; j < 32; ++j) {
                int idx = j * 256 + t;
                int row = idx >> 7, col = idx & 127;
                int o = o0 + (row >> 5) * 64 + pass * 32 + (row & 31);
                if constexpr (MODE == 1) {
                    Yf[((size_t)bb << 23) + (size_t)o * 16384 + nb + col] = ldsf[row * 132 + col];
                } else {
                    Yf[(size_t)o * ostride + m_loc + col] = ldsf[row * 132 + col];
                }
            }
        }
    }
}

// ---------------------------------------------------------------- launch
extern "C" void kernel_launch(void* const* d_in, const int* in_sizes, int n_in,
                              void* d_out, int out_size, void* d_ws, size_t ws_size,
                              hipStream_t stream) {
    const float* x     = (const float*)d_in[0];
    const float* proxy = (const float*)d_in[1];
    const float* pw1 = (const float*)d_in[2];
    const float* pg1 = (const float*)d_in[3];
    const float* pb1 = (const float*)d_in[4];
    const float* pm1 = (const float*)d_in[5];
    const float* pv1 = (const float*)d_in[6];
    const float* pw2 = (const float*)d_in[7];
    const float* pg2 = (const float*)d_in[8];
    const float* pb2 = (const float*)d_in[9];
    const float* pm2 = (const float*)d_in[10];
    const float* pv2 = (const float*)d_in[11];
    const float* ow1 = (const float*)d_in[12];
    const float* og1 = (const float*)d_in[13];
    const float* ob1 = (const float*)d_in[14];
    const float* om1 = (const float*)d_in[15];
    const float* ov1 = (const float*)d_in[16];
    const float* ow2 = (const float*)d_in[17];
    const float* og2 = (const float*)d_in[18];
    const float* ob2 = (const float*)d_in[19];
    const float* om2 = (const float*)d_in[20];
    const float* ov2 = (const float*)d_in[21];
    const float* dw  = (const float*)d_in[22];
    const float* dg  = (const float*)d_in[23];
    const float* db  = (const float*)d_in[24];
    const float* dm  = (const float*)d_in[25];
    const float* dv  = (const float*)d_in[26];
    const float* uw  = (const float*)d_in[27];
    const float* ug  = (const float*)d_in[28];
    const float* ub  = (const float*)d_in[29];
    const float* um  = (const float*)d_in[30];
    const float* uv  = (const float*)d_in[31];

    char* ws = (char*)d_ws;
    u16* wpw1h = (u16*)(ws + 0);               // 262144 B
    u16* wpw1l = (u16*)(ws + 262144);
    u16* wpw2h = (u16*)(ws + 524288);          // 131072 B
    u16* wpw2l = (u16*)(ws + 655360);
    u16* wuwh  = (u16*)(ws + 786432);          // 262144 B
    u16* wuwl  = (u16*)(ws + 1048576);
    float* kmat = (float*)(ws + 1310720);      // 155648 B
    float* vmat = (float*)(ws + 1466368);      // 155648 B -> ends 1622016
    u16* q1h = (u16*)(ws + 1703936);           // 67108864 B
    u16* q1l = (u16*)(ws + 68812800);          // 67108864 B -> ends 135921664
    float* q2f = (float*)(ws + 135921664ull);  // 134217728/passes B  (layout [256][chunk])
    u16* ctxh = q1h;                           // pass-disjoint alias
    u16* ctxl = q1l;

    int passes = 1;
    while (passes < 16 && 135921664ull + 134217728ull / (size_t)passes > ws_size) passes <<= 1;

    convert_split_kernel<<<512, 256, 0, stream>>>(pw1, wpw1h, wpw1l, 131072);
    convert_split_kernel<<<256, 256, 0, stream>>>(pw2, wpw2h, wpw2l, 65536);
    convert_split_kernel<<<512, 256, 0, stream>>>(uw,  wuwh,  wuwl,  131072);

    KVArgs ka{proxy, ow1, og1, ob1, om1, ov1, ow2, og2, ob2, om2, ov2,
              dw, dg, db, dm, dv, kmat, vmat};
    kv_kernel<<<8, 256, 0, stream>>>(ka);

    // gemm1: x (fp32, fused transpose+split) -> q1 (hi/lo planes), K=512
    gemm_kernel<512, 256, 0, 1><<<dim3(2, 1024), 256, 0, stream>>>(
        nullptr, nullptr, x, wpw1h, wpw1l, pg1, pb1, pm1, pv1, q1h, q1l, nullptr, 0, 0);

    const int mb = 1024 / passes;              // m-blocks per pass
    const int chunk = mb * 128;                // pixels per pass
    for (int p = 0; p < passes; ++p) {
        const int m_off = p * chunk;
        // gemm2: q1 -> q2t [256][chunk] fp32 transposed (coalesced), K=256
        gemm_kernel<256, 256, 2, 0><<<dim3(2, mb), 256, 0, stream>>>(
            q1h, q1l, nullptr, wpw2h, wpw2l, pg2, pb2, pm2, pv2, nullptr, nullptr, q2f, m_off, chunk);
        // attention: coalesced q reads (transposed q2), LDS-staged ctx stores
        AttnArgs aa{q2f, kmat, vmat, ctxh, ctxl, chunk, (long long)m_off};
        attn_kernel<<<mb * 2, 256, 0, stream>>>(aa);
    }

    // gemm_up: ctx -> out[b][o][n] fp32, K=256, COUT=512
    gemm_kernel<256, 512, 1, 0><<<dim3(4, 1024), 256, 0, stream>>>(
        ctxh, ctxl, nullptr, wuwh, wuwl, ug, ub, um, uv, nullptr, nullptr, (float*)d_out, 0, 16384);
}

// Round 6
// 1321.200 us; speedup vs baseline: 1.1798x; 1.1798x over previous
//
#include <hip/hip_runtime.h>

typedef unsigned int u32;
typedef unsigned short u16;
typedef __attribute__((ext_vector_type(8))) short bf16x8;
typedef __attribute__((ext_vector_type(4))) float f32x4;

#define DEVI static __device__ __forceinline__

DEVI u16 f2bf(float f) {
    u32 u = __float_as_uint(f);
    u32 r = u + 0x7FFFu + ((u >> 16) & 1u);   // RNE (inputs finite)
    return (u16)(r >> 16);
}
DEVI float bf2f(u16 s) { return __uint_as_float(((u32)s) << 16); }
DEVI void split2(float a, u16& h, u16& l) {   // a ≈ hi + lo, residual ≤ 2^-18|a|
    h = f2bf(a);
    l = f2bf(a - bf2f(h));
}
DEVI int swz(int row) { return (row & 3) ^ ((row >> 2) & 3); }  // 32-col-tile swizzle key

union U4 { uint4 v; u16 s[8]; };

// ---------------------------------------------------------------- f32 -> (hi,lo) bf16 planes
__global__ __launch_bounds__(256) void convert_split_kernel(const float* __restrict__ in,
                                                            u16* __restrict__ hi,
                                                            u16* __restrict__ lo, int n) {
    int i = blockIdx.x * 256 + threadIdx.x;
    if (i < n) { u16 h, l; split2(in[i], h, l); hi[i] = h; lo[i] = l; }
}

// ---------------------------------------------------------------- proxy-side K/V (tiny, fp32 VALU)
struct KVArgs {
    const float *proxy;
    const float *ow1, *og1, *ob1, *om1, *ov1;
    const float *ow2, *og2, *ob2, *om2, *ov2;
    const float *dw,  *dg,  *db,  *dm,  *dv;
    float *kmat;   // [B][256][19]
    float *vmat;   // [B][19][256]
};
__global__ __launch_bounds__(256) void kv_kernel(KVArgs a) {
    __shared__ float pl[512 * 19];
    __shared__ float t1[256 * 19];
    const int t = threadIdx.x;
    const int b = blockIdx.x;
    const float* pb = a.proxy + (size_t)b * 512 * 19;
    for (int i = t; i < 512 * 19; i += 256) pl[i] = pb[i];
    __syncthreads();
    const int o = t;
    {
        float acc[19] = {0.f};
        const float* wr = a.ow1 + (size_t)o * 512;
        for (int c = 0; c < 512; ++c) {
            float wv = wr[c];
#pragma unroll
            for (int kk = 0; kk < 19; ++kk) acc[kk] += wv * pl[c * 19 + kk];
        }
        float sc = a.og1[o] * __frsqrt_rn(a.ov1[o] + 1e-5f);
        float sh = a.ob1[o] - a.om1[o] * sc;
#pragma unroll
        for (int kk = 0; kk < 19; ++kk) t1[o * 19 + kk] = fmaxf(acc[kk] * sc + sh, 0.f);
    }
    __syncthreads();
    {
        float acc[19] = {0.f};
        const float* wr = a.ow2 + (size_t)o * 256;
        for (int c = 0; c < 256; ++c) {
            float wv = wr[c];
#pragma unroll
            for (int kk = 0; kk < 19; ++kk) acc[kk] += wv * t1[c * 19 + kk];
        }
        float sc = a.og2[o] * __frsqrt_rn(a.ov2[o] + 1e-5f);
        float sh = a.ob2[o] - a.om2[o] * sc;
#pragma unroll
        for (int kk = 0; kk < 19; ++kk)
            a.kmat[((size_t)b * 256 + o) * 19 + kk] = fmaxf(acc[kk] * sc + sh, 0.f);
    }
    {
        float acc[19] = {0.f};
        const float* wr = a.dw + (size_t)o * 512;
        for (int c = 0; c < 512; ++c) {
            float wv = wr[c];
#pragma unroll
            for (int kk = 0; kk < 19; ++kk) acc[kk] += wv * pl[c * 19 + kk];
        }
        float sc = a.dg[o] * __frsqrt_rn(a.dv[o] + 1e-5f);
        float sh = a.db[o] - a.dm[o] * sc;
#pragma unroll
        for (int kk = 0; kk < 19; ++kk)
            a.vmat[((size_t)b * 19 + kk) * 256 + o] = fmaxf(acc[kk] * sc + sh, 0.f);
    }
}

// ---------------------------------------------------------------- attention (fp32 q rows)
struct AttnArgs { const float* q2f; const float* kmat; const float* vmat;
                  u16* ctxh; u16* ctxl; long long p_off; };
__global__ __launch_bounds__(256) void attn_kernel(AttnArgs a) {
    __shared__ float kl[4864];   // [c][19]
    __shared__ float vl[4864];   // [kk][256]
    const int t = threadIdx.x;
    const size_t pl_ = (size_t)blockIdx.x * 256;          // pass-local pixel base
    const size_t pg  = (size_t)a.p_off + pl_;             // global pixel base
    const int b = (int)(pg >> 14);
    for (int i = t; i < 4864; i += 256) { kl[i] = a.kmat[(size_t)b * 4864 + i];
                                          vl[i] = a.vmat[(size_t)b * 4864 + i]; }
    __syncthreads();
    const float* qrow = a.q2f + (pl_ + t) * 256;          // pass-local fp32 row, 1 KB
    float sim[19];
#pragma unroll
    for (int kk = 0; kk < 19; ++kk) sim[kk] = 0.f;
    for (int j = 0; j < 64; ++j) {
        float4 qv = reinterpret_cast<const float4*>(qrow)[j];
#pragma unroll
        for (int e = 0; e < 4; ++e) {
            float qf = (e == 0) ? qv.x : (e == 1) ? qv.y : (e == 2) ? qv.z : qv.w;
            int c = j * 4 + e;
#pragma unroll
            for (int kk = 0; kk < 19; ++kk) sim[kk] += qf * kl[c * 19 + kk];
        }
    }
    float mx = -1e30f;
#pragma unroll
    for (int kk = 0; kk < 19; ++kk) { sim[kk] *= 0.0625f; mx = fmaxf(mx, sim[kk]); }
    float ssum = 0.f;
#pragma unroll
    for (int kk = 0; kk < 19; ++kk) { sim[kk] = __expf(sim[kk] - mx); ssum += sim[kk]; }
    const float inv = 1.f / ssum;
#pragma unroll
    for (int kk = 0; kk < 19; ++kk) sim[kk] *= inv;
    u16* crh = a.ctxh + (pg + t) * 256;
    u16* crl = a.ctxl + (pg + t) * 256;
    for (int j = 0; j < 32; ++j) {
        U4 hh, ll;
#pragma unroll
        for (int e = 0; e < 8; ++e) {
            int c = j * 8 + e;
            float acc = 0.f;
#pragma unroll
            for (int kk = 0; kk < 19; ++kk) acc += sim[kk] * vl[kk * 256 + c];
            split2(acc, hh.s[e], ll.s[e]);
        }
        *reinterpret_cast<uint4*>(crh + j * 8) = hh.v;
        *reinterpret_cast<uint4*>(crl + j * 8) = ll.v;
    }
}

// ---------------------------------------------------------------- FUSED gemm1+gemm2 (x -> q1[regs/LDS] -> q2 fp32)
// Block = 128 px, full o-range 256 for both layers. No q1 HBM round-trip.
// Wave layout L1: wr = px-half, wc = o1-half; acc1[4][8].
// Phase 2 per px-quarter: q1 -> LDS (swizzled), gemm2 all-wave (o2-quarter each), q2 fp32 full rows.
struct F12Args {
    const float* Xf;
    const u16 *W1h, *W1l, *W2h, *W2l;
    const float *g1, *b1, *m1, *v1;
    const float *g2, *b2, *m2, *v2;
    float* q2f;     // pass-local [chunk][256] fp32
    int m_off;
};
__global__ __launch_bounds__(256, 1) void fused12_kernel(F12Args a) {
    __shared__ char LB[65536];
    u16* xs  = (u16*)LB;             // phase1: [2][128][32] u16 (16 KB)
    u16* wb  = (u16*)(LB + 16384);   // phase1: [2][256][32] u16 (32 KB)
    u16* q1  = (u16*)LB;             // phase2: [2][32][256] u16 (32 KB)
    u16* wb2 = (u16*)(LB + 32768);   // phase2: [2][256][32] u16 (32 KB)
    float* tf = (float*)LB;          // epilogue: [32][256] f32 (32 KB)

    const int t = threadIdx.x;
    const int l = t & 63, w = t >> 6;
    const int wr = w >> 1, wc = w & 1;
    const int l15 = l & 15, l4 = l >> 4;
    const int mloc = blockIdx.x * 128;
    const int mg = a.m_off + mloc;
    const int bb = mg >> 14, nb = mg & 16383;

    f32x4 acc1[4][8];
#pragma unroll
    for (int mi = 0; mi < 4; ++mi)
#pragma unroll
        for (int ni = 0; ni < 8; ++ni) acc1[mi][ni] = f32x4{0.f, 0.f, 0.f, 0.f};

    float fx[2][8];
    uint4 rh[4], rl[4];

    auto loadX = [&](int s) {
#pragma unroll
        for (int i = 0; i < 2; ++i) {
            int task = t + 256 * i;                 // 512 tasks: px(128) x oct(4)
            int px = task & 127, oct = task >> 7;
            const float* src = a.Xf + (((size_t)bb * 512 + s * 32 + oct * 8) << 14) + nb + px;
#pragma unroll
            for (int e = 0; e < 8; ++e) fx[i][e] = src[(size_t)e << 14];
        }
    };
    auto writeX = [&]() {
#pragma unroll
        for (int i = 0; i < 2; ++i) {
            int task = t + 256 * i;
            int px = task & 127, oct = task >> 7;
            U4 ph, plo;
#pragma unroll
            for (int e = 0; e < 8; ++e) split2(fx[i][e], ph.s[e], plo.s[e]);
            int pos = px * 32 + ((oct ^ swz(px)) * 8);
            *reinterpret_cast<uint4*>(&xs[pos]) = ph.v;
            *reinterpret_cast<uint4*>(&xs[4096 + pos]) = plo.v;
        }
    };
    auto loadW1 = [&](int s) {
#pragma unroll
        for (int i = 0; i < 4; ++i) {
            int task = t + 256 * i;                 // 1024 tasks: row(256) x chunk(4)
            int row = task >> 2, c = task & 3;
            size_t off = (size_t)row * 512 + s * 32 + c * 8;
            rh[i] = *reinterpret_cast<const uint4*>(&a.W1h[off]);
            rl[i] = *reinterpret_cast<const uint4*>(&a.W1l[off]);
        }
    };
    auto writeW1 = [&]() {
#pragma unroll
        for (int i = 0; i < 4; ++i) {
            int task = t + 256 * i;
            int row = task >> 2, c = task & 3;
            int pos = row * 32 + ((c ^ swz(row)) * 8);
            *reinterpret_cast<uint4*>(&wb[pos]) = rh[i];
            *reinterpret_cast<uint4*>(&wb[8192 + pos]) = rl[i];
        }
    };

    // ---------------- phase 1: q1 = relu(bn1(x . W1)), K=512 in 16 steps of 32
    loadX(0); loadW1(0);
    writeX(); writeW1();
    __syncthreads();
    for (int s = 0; s < 16; ++s) {
        if (s < 15) { loadX(s + 1); loadW1(s + 1); }   // issue under MFMA
        bf16x8 ah[4], am[4];
#pragma unroll
        for (int mi = 0; mi < 4; ++mi) {
            int ar = wr * 64 + mi * 16 + l15;
            int ap = ar * 32 + ((l4 ^ swz(ar)) * 8);
            ah[mi] = *reinterpret_cast<const bf16x8*>(&xs[ap]);
            am[mi] = *reinterpret_cast<const bf16x8*>(&xs[4096 + ap]);
        }
#pragma unroll
        for (int ni = 0; ni < 8; ++ni) {
            int br = wc * 128 + ni * 16 + l15;
            int bp = br * 32 + ((l4 ^ swz(br)) * 8);
            bf16x8 bh = *reinterpret_cast<const bf16x8*>(&wb[bp]);
            bf16x8 bl_ = *reinterpret_cast<const bf16x8*>(&wb[8192 + bp]);
#pragma unroll
            for (int mi = 0; mi < 4; ++mi) {
                acc1[mi][ni] = __builtin_amdgcn_mfma_f32_16x16x32_bf16(ah[mi], bh, acc1[mi][ni], 0, 0, 0);
                acc1[mi][ni] = __builtin_amdgcn_mfma_f32_16x16x32_bf16(ah[mi], bl_, acc1[mi][ni], 0, 0, 0);
                acc1[mi][ni] = __builtin_amdgcn_mfma_f32_16x16x32_bf16(am[mi], bh, acc1[mi][ni], 0, 0, 0);
            }
        }
        __syncthreads();
        if (s < 15) { writeX(); writeW1(); __syncthreads(); }
    }

    // BN coefficients
    float scl1[8], shf1[8];
#pragma unroll
    for (int ni = 0; ni < 8; ++ni) {
        int o = wc * 128 + ni * 16 + l15;
        scl1[ni] = a.g1[o] * __frsqrt_rn(a.v1[o] + 1e-5f);
        shf1[ni] = a.b1[o] - a.m1[o] * scl1[ni];
    }
    float scl2[4], shf2[4];
#pragma unroll
    for (int ni = 0; ni < 4; ++ni) {
        int o = w * 64 + ni * 16 + l15;
        scl2[ni] = a.g2[o] * __frsqrt_rn(a.v2[o] + 1e-5f);
        shf2[ni] = a.b2[o] - a.m2[o] * scl2[ni];
    }

    auto loadW2 = [&](int s2) {
#pragma unroll
        for (int i = 0; i < 4; ++i) {
            int task = t + 256 * i;
            int row = task >> 2, c = task & 3;
            size_t off = (size_t)row * 256 + s2 * 32 + c * 8;
            rh[i] = *reinterpret_cast<const uint4*>(&a.W2h[off]);
            rl[i] = *reinterpret_cast<const uint4*>(&a.W2l[off]);
        }
    };
    auto writeW2 = [&]() {
#pragma unroll
        for (int i = 0; i < 4; ++i) {
            int task = t + 256 * i;
            int row = task >> 2, c = task & 3;
            int pos = row * 32 + ((c ^ swz(row)) * 8);
            *reinterpret_cast<uint4*>(&wb2[pos]) = rh[i];
            *reinterpret_cast<uint4*>(&wb2[8192 + pos]) = rl[i];
        }
    };

    // ---------------- phase 2: per px-quarter, q1->LDS then q2 = relu(bn2(q1 . W2))
#pragma unroll
    for (int pxq = 0; pxq < 4; ++pxq) {
        __syncthreads();                       // prior LDS users done
        loadW2(0);
        if (wr == (pxq >> 1)) {                // this wave's px-half holds the quarter
#pragma unroll
            for (int dm = 0; dm < 2; ++dm) {
                const int mi = (pxq & 1) * 2 + dm;
#pragma unroll
                for (int ni = 0; ni < 8; ++ni) {
                    int o1 = wc * 128 + ni * 16 + l15;
                    int sub = (o1 >> 5) * 32, cc = (o1 >> 3) & 3, ee = o1 & 7;
#pragma unroll
                    for (int r = 0; r < 4; ++r) {
                        int px_l = dm * 16 + l4 * 4 + r;
                        float y = fmaxf(acc1[mi][ni][r] * scl1[ni] + shf1[ni], 0.f);
                        u16 h, lo; split2(y, h, lo);
                        int pos = px_l * 256 + sub + ((cc ^ swz(px_l)) * 8) + ee;
                        q1[pos] = h;
                        q1[8192 + pos] = lo;
                    }
                }
            }
        }
        writeW2();
        __syncthreads();

        f32x4 acc2[2][4];
#pragma unroll
        for (int mi2 = 0; mi2 < 2; ++mi2)
#pragma unroll
            for (int ni = 0; ni < 4; ++ni) acc2[mi2][ni] = f32x4{0.f, 0.f, 0.f, 0.f};

        for (int s2 = 0; s2 < 8; ++s2) {       // K2 = 256 in 8 steps of 32
            if (s2 < 7) loadW2(s2 + 1);
            bf16x8 a2h[2], a2m[2];
#pragma unroll
            for (int mi2 = 0; mi2 < 2; ++mi2) {
                int ar = mi2 * 16 + l15;
                int ap = ar * 256 + s2 * 32 + ((l4 ^ swz(ar)) * 8);
                a2h[mi2] = *reinterpret_cast<const bf16x8*>(&q1[ap]);
                a2m[mi2] = *reinterpret_cast<const bf16x8*>(&q1[8192 + ap]);
            }
#pragma unroll
            for (int ni = 0; ni < 4; ++ni) {
                int br = w * 64 + ni * 16 + l15;
                int bp = br * 32 + ((l4 ^ swz(br)) * 8);
                bf16x8 b2h = *reinterpret_cast<const bf16x8*>(&wb2[bp]);
                bf16x8 b2l = *reinterpret_cast<const bf16x8*>(&wb2[8192 + bp]);
#pragma unroll
                for (int mi2 = 0; mi2 < 2; ++mi2) {
                    acc2[mi2][ni] = __builtin_amdgcn_mfma_f32_16x16x32_bf16(a2h[mi2], b2h, acc2[mi2][ni], 0, 0, 0);
                    acc2[mi2][ni] = __builtin_amdgcn_mfma_f32_16x16x32_bf16(a2h[mi2], b2l, acc2[mi2][ni], 0, 0, 0);
                    acc2[mi2][ni] = __builtin_amdgcn_mfma_f32_16x16x32_bf16(a2m[mi2], b2h, acc2[mi2][ni], 0, 0, 0);
                }
            }
            __syncthreads();
            if (s2 < 7) { writeW2(); __syncthreads(); }
        }

        // q2 epilogue: BN2+ReLU -> LDS f32 tile -> coalesced full-row stores
#pragma unroll
        for (int mi2 = 0; mi2 < 2; ++mi2)
#pragma unroll
            for (int ni = 0; ni < 4; ++ni) {
                int o2 = w * 64 + ni * 16 + l15;
#pragma unroll
                for (int r = 0; r < 4; ++r) {
                    int px_l = mi2 * 16 + l4 * 4 + r;
                    tf[px_l * 256 + o2] = fmaxf(acc2[mi2][ni][r] * scl2[ni] + shf2[ni], 0.f);
                }
            }
        __syncthreads();
#pragma unroll
        for (int j = 0; j < 8; ++j) {
            int task = j * 256 + t;
            int row = task >> 6, c4 = task & 63;
            *reinterpret_cast<float4*>(&a.q2f[(size_t)(mloc + pxq * 32 + row) * 256 + c4 * 4]) =
                *reinterpret_cast<const float4*>(&tf[row * 256 + c4 * 4]);
        }
    }
}

// ---------------------------------------------------------------- split-bf16 MFMA GEMM (gemm_up only: MODE 1, ASRC 0)
template<int K, int COUT, int MODE, int ASRC>
__global__ __launch_bounds__(256, 2)
void gemm_kernel(const u16* __restrict__ Ah, const u16* __restrict__ Al,
                 const float* __restrict__ Xf,
                 const u16* __restrict__ Wh, const u16* __restrict__ Wl,
                 const float* __restrict__ gg, const float* __restrict__ bbv,
                 const float* __restrict__ mmv, const float* __restrict__ vvv,
                 u16* __restrict__ Yh, u16* __restrict__ Yl,
                 float* __restrict__ Yf, int m_off, int ostride) {
    static_assert(K % 64 == 0, "");
    constexpr int NT = K / 64;
    __shared__ u16 lds[4][128 * 64];
    const int t = threadIdx.x;
    const int l = t & 63;
    const int w = t >> 6;
    const int wr = w >> 1, wc = w & 1;
    const int l15 = l & 15, l4 = l >> 4;
    const int o0 = blockIdx.x * 128;
    const int m_loc = blockIdx.y * 128;
    const int m_glob = m_off + m_loc;
    const int bb = m_glob >> 14;
    const int nb = m_glob & 16383;

    f32x4 acc[4][4];
#pragma unroll
    for (int mi = 0; mi < 4; ++mi)
#pragma unroll
        for (int ni = 0; ni < 4; ++ni) acc[mi][ni] = f32x4{0.f, 0.f, 0.f, 0.f};

    uint4 rah[4], ral[4], rbh[4], rbl[4];

    auto stage_load = [&](int kt) {
#pragma unroll
        for (int i = 0; i < 4; ++i) {
            int cidx = t + 256 * i, row = cidx >> 3, cg = cidx & 7;
            size_t off = (size_t)(m_glob + row) * K + kt * 64 + cg * 8;
            rah[i] = *reinterpret_cast<const uint4*>(Ah + off);
            ral[i] = *reinterpret_cast<const uint4*>(Al + off);
        }
#pragma unroll
        for (int i = 0; i < 4; ++i) {
            int cidx = t + 256 * i, row = cidx >> 3, cg = cidx & 7;
            size_t off = (size_t)(o0 + row) * K + kt * 64 + cg * 8;
            rbh[i] = *reinterpret_cast<const uint4*>(Wh + off);
            rbl[i] = *reinterpret_cast<const uint4*>(Wl + off);
        }
    };
    auto stage_write = [&]() {
#pragma unroll
        for (int i = 0; i < 4; ++i) {
            int cidx = t + 256 * i, row = cidx >> 3, cg = cidx & 7;
            int sc = row * 64 + ((cg ^ (row & 7)) * 8);
            *reinterpret_cast<uint4*>(&lds[0][sc]) = rah[i];
            *reinterpret_cast<uint4*>(&lds[1][sc]) = ral[i];
        }
#pragma unroll
        for (int i = 0; i < 4; ++i) {
            int cidx = t + 256 * i, row = cidx >> 3, cg = cidx & 7;
            int sc = row * 64 + ((cg ^ (row & 7)) * 8);
            *reinterpret_cast<uint4*>(&lds[2][sc]) = rbh[i];
            *reinterpret_cast<uint4*>(&lds[3][sc]) = rbl[i];
        }
    };

    stage_load(0);
    stage_write();
    __syncthreads();

    for (int kt = 0; kt < NT; ++kt) {
        const bool more = (kt + 1 < NT);
        if (more) stage_load(kt + 1);
#pragma unroll
        for (int kk = 0; kk < 2; ++kk) {
            bf16x8 ah[4], al[4], bh[4], bl[4];
#pragma unroll
            for (int mi = 0; mi < 4; ++mi) {
                int row = wr * 64 + mi * 16 + l15;
                int idx = row * 64 + (((kk * 4 + l4) ^ (row & 7)) * 8);
                ah[mi] = *reinterpret_cast<const bf16x8*>(&lds[0][idx]);
                al[mi] = *reinterpret_cast<const bf16x8*>(&lds[1][idx]);
            }
#pragma unroll
            for (int ni = 0; ni < 4; ++ni) {
                int row = wc * 64 + ni * 16 + l15;
                int idx = row * 64 + (((kk * 4 + l4) ^ (row & 7)) * 8);
                bh[ni] = *reinterpret_cast<const bf16x8*>(&lds[2][idx]);
                bl[ni] = *reinterpret_cast<const bf16x8*>(&lds[3][idx]);
            }
#pragma unroll
            for (int mi = 0; mi < 4; ++mi)
#pragma unroll
                for (int ni = 0; ni < 4; ++ni) {
                    acc[mi][ni] = __builtin_amdgcn_mfma_f32_16x16x32_bf16(ah[mi], bh[ni], acc[mi][ni], 0, 0, 0);
                    acc[mi][ni] = __builtin_amdgcn_mfma_f32_16x16x32_bf16(ah[mi], bl[ni], acc[mi][ni], 0, 0, 0);
                    acc[mi][ni] = __builtin_amdgcn_mfma_f32_16x16x32_bf16(al[mi], bh[ni], acc[mi][ni], 0, 0, 0);
                }
        }
        __syncthreads();
        if (more) { stage_write(); __syncthreads(); }
    }

    float scl[4], shf[4];
#pragma unroll
    for (int ni = 0; ni < 4; ++ni) {
        int o = o0 + wc * 64 + ni * 16 + l15;
        scl[ni] = gg[o] * __frsqrt_rn(vvv[o] + 1e-5f);
        shf[ni] = bbv[o] - mmv[o] * scl[ni];
    }

    // transpose epilogue via LDS [64][132] f32 -> out[b][o][16384]
    float* ldsf = reinterpret_cast<float*>(&lds[0][0]);
#pragma unroll 1
    for (int pass = 0; pass < 2; ++pass) {
        __syncthreads();
#pragma unroll
        for (int nj = 0; nj < 2; ++nj) {
            int ni = pass * 2 + nj;
            int lrow = wc * 32 + nj * 16 + l15;
            int lcolb = wr * 64 + l4 * 4;
#pragma unroll
            for (int mi = 0; mi < 4; ++mi)
#pragma unroll
                for (int r = 0; r < 4; ++r) {
                    float y = fmaxf(acc[mi][ni][r] * scl[ni] + shf[ni], 0.f);
                    ldsf[lrow * 132 + lcolb + mi * 16 + r] = y;
                }
        }
        __syncthreads();
#pragma unroll
        for (int j = 0; j < 32; ++j) {
            int idx = j * 256 + t;
            int row = idx >> 7, col = idx & 127;
            int o = o0 + (row >> 5) * 64 + pass * 32 + (row & 31);
            Yf[((size_t)bb << 23) + (size_t)o * 16384 + nb + col] = ldsf[row * 132 + col];
        }
    }
}

// ---------------------------------------------------------------- launch
extern "C" void kernel_launch(void* const* d_in, const int* in_sizes, int n_in,
                              void* d_out, int out_size, void* d_ws, size_t ws_size,
                              hipStream_t stream) {
    const float* x     = (const float*)d_in[0];
    const float* proxy = (const float*)d_in[1];
    const float* pw1 = (const float*)d_in[2];
    const float* pg1 = (const float*)d_in[3];
    const float* pb1 = (const float*)d_in[4];
    const float* pm1 = (const float*)d_in[5];
    const float* pv1 = (const float*)d_in[6];
    const float* pw2 = (const float*)d_in[7];
    const float* pg2 = (const float*)d_in[8];
    const float* pb2 = (const float*)d_in[9];
    const float* pm2 = (const float*)d_in[10];
    const float* pv2 = (const float*)d_in[11];
    const float* ow1 = (const float*)d_in[12];
    const float* og1 = (const float*)d_in[13];
    const float* ob1 = (const float*)d_in[14];
    const float* om1 = (const float*)d_in[15];
    const float* ov1 = (const float*)d_in[16];
    const float* ow2 = (const float*)d_in[17];
    const float* og2 = (const float*)d_in[18];
    const float* ob2 = (const float*)d_in[19];
    const float* om2 = (const float*)d_in[20];
    const float* ov2 = (const float*)d_in[21];
    const float* dw  = (const float*)d_in[22];
    const float* dg  = (const float*)d_in[23];
    const float* db  = (const float*)d_in[24];
    const float* dm  = (const float*)d_in[25];
    const float* dv  = (const float*)d_in[26];
    const float* uw  = (const float*)d_in[27];
    const float* ug  = (const float*)d_in[28];
    const float* ub  = (const float*)d_in[29];
    const float* um  = (const float*)d_in[30];
    const float* uv  = (const float*)d_in[31];

    char* ws = (char*)d_ws;
    u16* wpw1h = (u16*)(ws + 0);                 // 262144 B
    u16* wpw1l = (u16*)(ws + 262144);
    u16* wpw2h = (u16*)(ws + 524288);            // 131072 B
    u16* wpw2l = (u16*)(ws + 655360);
    u16* wuwh  = (u16*)(ws + 786432);            // 262144 B
    u16* wuwl  = (u16*)(ws + 1048576);
    float* kmat = (float*)(ws + 1310720);        // 155648 B
    float* vmat = (float*)(ws + 1466368);        // 155648 B -> ends 1622016
    u16* ctxh = (u16*)(ws + 2097152);            // 67108864 B
    u16* ctxl = (u16*)(ws + 69206016);           // 67108864 B -> ends 136314880
    float* q2f = (float*)(ws + 136314880ull);    // 134217728/passes B, [chunk][256] fp32

    int passes = 1;
    while (passes < 16 && 136314880ull + 134217728ull / (size_t)passes > ws_size) passes <<= 1;

    convert_split_kernel<<<512, 256, 0, stream>>>(pw1, wpw1h, wpw1l, 131072);
    convert_split_kernel<<<256, 256, 0, stream>>>(pw2, wpw2h, wpw2l, 65536);
    convert_split_kernel<<<512, 256, 0, stream>>>(uw,  wuwh,  wuwl,  131072);

    KVArgs ka{proxy, ow1, og1, ob1, om1, ov1, ow2, og2, ob2, om2, ov2,
              dw, dg, db, dm, dv, kmat, vmat};
    kv_kernel<<<8, 256, 0, stream>>>(ka);

    const int mb = 1024 / passes;                // 128-px blocks per pass
    for (int p = 0; p < passes; ++p) {
        const int m_off = p * mb * 128;
        F12Args fa{x, wpw1h, wpw1l, wpw2h, wpw2l,
                   pg1, pb1, pm1, pv1, pg2, pb2, pm2, pv2, q2f, m_off};
        fused12_kernel<<<mb, 256, 0, stream>>>(fa);
        AttnArgs aa{q2f, kmat, vmat, ctxh, ctxl, (long long)m_off};
        attn_kernel<<<mb / 2, 256, 0, stream>>>(aa);
    }

    // gemm_up: ctx -> out[b][o][n] fp32, K=256, COUT=512
    gemm_kernel<256, 512, 1, 0><<<dim3(4, 1024), 256, 0, stream>>>(
        ctxh, ctxl, nullptr, wuwh, wuwl, ug, ub, um, uv, nullptr, nullptr, (float*)d_out, 0, 16384);
}

// Round 8
// 1151.728 us; speedup vs baseline: 1.3534x; 1.1471x over previous
//
#include <hip/hip_runtime.h>

typedef unsigned int u32;
typedef unsigned short u16;
typedef __attribute__((ext_vector_type(8))) short bf16x8;
typedef __attribute__((ext_vector_type(4))) float f32x4;

#define DEVI static __device__ __forceinline__

DEVI u16 f2bf(float f) {
    u32 u = __float_as_uint(f);
    u32 r = u + 0x7FFFu + ((u >> 16) & 1u);   // RNE (inputs finite)
    return (u16)(r >> 16);
}
DEVI float bf2f(u16 s) { return __uint_as_float(((u32)s) << 16); }
DEVI void split2(float a, u16& h, u16& l) {   // a ≈ hi + lo, residual ≤ 2^-18|a|
    h = f2bf(a);
    l = f2bf(a - bf2f(h));
}
DEVI int swz(int row) { return (row & 3) ^ ((row >> 2) & 3); }  // 32-col-tile swizzle key

// direct global->LDS DMA, 16 B/lane; LDS dest = wave-uniform base + lane*16
DEVI void gload16(const void* g, void* l) {
    __builtin_amdgcn_global_load_lds(
        (const __attribute__((address_space(1))) u32*)g,
        (__attribute__((address_space(3))) u32*)l, 16, 0, 0);
}

union U4 { uint4 v; u16 s[8]; };

// ---------------------------------------------------------------- f32 -> (hi,lo) bf16 planes
__global__ __launch_bounds__(256) void convert_split_kernel(const float* __restrict__ in,
                                                            u16* __restrict__ hi,
                                                            u16* __restrict__ lo, int n) {
    int i = blockIdx.x * 256 + threadIdx.x;
    if (i < n) { u16 h, l; split2(in[i], h, l); hi[i] = h; lo[i] = l; }
}

// ---------------------------------------------------------------- proxy-side K/V (tiny, fp32 VALU)
struct KVArgs {
    const float *proxy;
    const float *ow1, *og1, *ob1, *om1, *ov1;
    const float *ow2, *og2, *ob2, *om2, *ov2;
    const float *dw,  *dg,  *db,  *dm,  *dv;
    float *kmat;   // [B][256][19]
    float *vmat;   // [B][19][256]
};
__global__ __launch_bounds__(256) void kv_kernel(KVArgs a) {
    __shared__ float pl[512 * 19];
    __shared__ float t1[256 * 19];
    const int t = threadIdx.x;
    const int b = blockIdx.x;
    const float* pb = a.proxy + (size_t)b * 512 * 19;
    for (int i = t; i < 512 * 19; i += 256) pl[i] = pb[i];
    __syncthreads();
    const int o = t;
    {
        float acc[19] = {0.f};
        const float* wr = a.ow1 + (size_t)o * 512;
        for (int c = 0; c < 512; ++c) {
            float wv = wr[c];
#pragma unroll
            for (int kk = 0; kk < 19; ++kk) acc[kk] += wv * pl[c * 19 + kk];
        }
        float sc = a.og1[o] * __frsqrt_rn(a.ov1[o] + 1e-5f);
        float sh = a.ob1[o] - a.om1[o] * sc;
#pragma unroll
        for (int kk = 0; kk < 19; ++kk) t1[o * 19 + kk] = fmaxf(acc[kk] * sc + sh, 0.f);
    }
    __syncthreads();
    {
        float acc[19] = {0.f};
        const float* wr = a.ow2 + (size_t)o * 256;
        for (int c = 0; c < 256; ++c) {
            float wv = wr[c];
#pragma unroll
            for (int kk = 0; kk < 19; ++kk) acc[kk] += wv * t1[c * 19 + kk];
        }
        float sc = a.og2[o] * __frsqrt_rn(a.ov2[o] + 1e-5f);
        float sh = a.ob2[o] - a.om2[o] * sc;
#pragma unroll
        for (int kk = 0; kk < 19; ++kk)
            a.kmat[((size_t)b * 256 + o) * 19 + kk] = fmaxf(acc[kk] * sc + sh, 0.f);
    }
    {
        float acc[19] = {0.f};
        const float* wr = a.dw + (size_t)o * 512;
        for (int c = 0; c < 512; ++c) {
            float wv = wr[c];
#pragma unroll
            for (int kk = 0; kk < 19; ++kk) acc[kk] += wv * pl[c * 19 + kk];
        }
        float sc = a.dg[o] * __frsqrt_rn(a.dv[o] + 1e-5f);
        float sh = a.db[o] - a.dm[o] * sc;
#pragma unroll
        for (int kk = 0; kk < 19; ++kk)
            a.vmat[((size_t)b * 19 + kk) * 256 + o] = fmaxf(acc[kk] * sc + sh, 0.f);
    }
}

// ---------------------------------------------------------------- attention (fp32 q rows)
struct AttnArgs { const float* q2f; const float* kmat; const float* vmat;
                  u16* ctxh; u16* ctxl; long long p_off; };
__global__ __launch_bounds__(256) void attn_kernel(AttnArgs a) {
    __shared__ float kl[4864];   // [c][19]
    __shared__ float vl[4864];   // [kk][256]
    const int t = threadIdx.x;
    const size_t pl_ = (size_t)blockIdx.x * 256;          // pass-local pixel base
    const size_t pg  = (size_t)a.p_off + pl_;             // global pixel base
    const int b = (int)(pg >> 14);
    for (int i = t; i < 4864; i += 256) { kl[i] = a.kmat[(size_t)b * 4864 + i];
                                          vl[i] = a.vmat[(size_t)b * 4864 + i]; }
    __syncthreads();
    const float* qrow = a.q2f + (pl_ + t) * 256;          // pass-local fp32 row, 1 KB
    float sim[19];
#pragma unroll
    for (int kk = 0; kk < 19; ++kk) sim[kk] = 0.f;
    for (int j = 0; j < 64; ++j) {
        float4 qv = reinterpret_cast<const float4*>(qrow)[j];
#pragma unroll
        for (int e = 0; e < 4; ++e) {
            float qf = (e == 0) ? qv.x : (e == 1) ? qv.y : (e == 2) ? qv.z : qv.w;
            int c = j * 4 + e;
#pragma unroll
            for (int kk = 0; kk < 19; ++kk) sim[kk] += qf * kl[c * 19 + kk];
        }
    }
    float mx = -1e30f;
#pragma unroll
    for (int kk = 0; kk < 19; ++kk) { sim[kk] *= 0.0625f; mx = fmaxf(mx, sim[kk]); }
    float ssum = 0.f;
#pragma unroll
    for (int kk = 0; kk < 19; ++kk) { sim[kk] = __expf(sim[kk] - mx); ssum += sim[kk]; }
    const float inv = 1.f / ssum;
#pragma unroll
    for (int kk = 0; kk < 19; ++kk) sim[kk] *= inv;
    u16* crh = a.ctxh + (pg + t) * 256;
    u16* crl = a.ctxl + (pg + t) * 256;
    for (int j = 0; j < 32; ++j) {
        U4 hh, ll;
#pragma unroll
        for (int e = 0; e < 8; ++e) {
            int c = j * 8 + e;
            float acc = 0.f;
#pragma unroll
            for (int kk = 0; kk < 19; ++kk) acc += sim[kk] * vl[kk * 256 + c];
            split2(acc, hh.s[e], ll.s[e]);
        }
        *reinterpret_cast<uint4*>(crh + j * 8) = hh.v;
        *reinterpret_cast<uint4*>(crl + j * 8) = ll.v;
    }
}

// ---------------------------------------------------------------- FUSED gemm1+gemm2 (x -> q1[regs/LDS] -> q2 fp32)
struct F12Args {
    const float* Xf;
    const u16 *W1h, *W1l, *W2h, *W2l;
    const float *g1, *b1, *m1, *v1;
    const float *g2, *b2, *m2, *v2;
    float* q2f;     // pass-local [chunk][256] fp32
    int m_off;
};
__global__ __launch_bounds__(256, 1) void fused12_kernel(F12Args a) {
    __shared__ char LB[65536];
    u16* xs  = (u16*)LB;             // phase1: [2][128][32] u16 (16 KB)
    u16* wb  = (u16*)(LB + 16384);   // phase1: [2][256][32] u16 (32 KB)
    u16* q1  = (u16*)LB;             // phase2: [2][32][256] u16 (32 KB)
    u16* wb2 = (u16*)(LB + 32768);   // phase2: [2][256][32] u16 (32 KB)
    float* tf = (float*)LB;          // epilogue: [32][256] f32 (32 KB)

    const int t = threadIdx.x;
    const int l = t & 63, w = t >> 6;
    const int wr = w >> 1, wc = w & 1;
    const int l15 = l & 15, l4 = l >> 4;
    const int mloc = blockIdx.x * 128;
    const int mg = a.m_off + mloc;
    const int bb = mg >> 14, nb = mg & 16383;

    f32x4 acc1[4][8];
#pragma unroll
    for (int mi = 0; mi < 4; ++mi)
#pragma unroll
        for (int ni = 0; ni < 8; ++ni) acc1[mi][ni] = f32x4{0.f, 0.f, 0.f, 0.f};

    float fx[2][8];
    uint4 rh[4], rl[4];

    auto loadX = [&](int s) {
#pragma unroll
        for (int i = 0; i < 2; ++i) {
            int task = t + 256 * i;                 // 512 tasks: px(128) x oct(4)
            int px = task & 127, oct = task >> 7;
            const float* src = a.Xf + (((size_t)bb * 512 + s * 32 + oct * 8) << 14) + nb + px;
#pragma unroll
            for (int e = 0; e < 8; ++e) fx[i][e] = src[(size_t)e << 14];
        }
    };
    auto writeX = [&]() {
#pragma unroll
        for (int i = 0; i < 2; ++i) {
            int task = t + 256 * i;
            int px = task & 127, oct = task >> 7;
            U4 ph, plo;
#pragma unroll
            for (int e = 0; e < 8; ++e) split2(fx[i][e], ph.s[e], plo.s[e]);
            int pos = px * 32 + ((oct ^ swz(px)) * 8);
            *reinterpret_cast<uint4*>(&xs[pos]) = ph.v;
            *reinterpret_cast<uint4*>(&xs[4096 + pos]) = plo.v;
        }
    };
    auto loadW1 = [&](int s) {
#pragma unroll
        for (int i = 0; i < 4; ++i) {
            int task = t + 256 * i;                 // 1024 tasks: row(256) x chunk(4)
            int row = task >> 2, c = task & 3;
            size_t off = (size_t)row * 512 + s * 32 + c * 8;
            rh[i] = *reinterpret_cast<const uint4*>(&a.W1h[off]);
            rl[i] = *reinterpret_cast<const uint4*>(&a.W1l[off]);
        }
    };
    auto writeW1 = [&]() {
#pragma unroll
        for (int i = 0; i < 4; ++i) {
            int task = t + 256 * i;
            int row = task >> 2, c = task & 3;
            int pos = row * 32 + ((c ^ swz(row)) * 8);
            *reinterpret_cast<uint4*>(&wb[pos]) = rh[i];
            *reinterpret_cast<uint4*>(&wb[8192 + pos]) = rl[i];
        }
    };

    // ---------------- phase 1: q1 = relu(bn1(x . W1)), K=512 in 16 steps of 32
    loadX(0); loadW1(0);
    writeX(); writeW1();
    __syncthreads();
    for (int s = 0; s < 16; ++s) {
        if (s < 15) { loadX(s + 1); loadW1(s + 1); }   // issue under MFMA
        bf16x8 ah[4], am[4];
#pragma unroll
        for (int mi = 0; mi < 4; ++mi) {
            int ar = wr * 64 + mi * 16 + l15;
            int ap = ar * 32 + ((l4 ^ swz(ar)) * 8);
            ah[mi] = *reinterpret_cast<const bf16x8*>(&xs[ap]);
            am[mi] = *reinterpret_cast<const bf16x8*>(&xs[4096 + ap]);
        }
#pragma unroll
        for (int ni = 0; ni < 8; ++ni) {
            int br = wc * 128 + ni * 16 + l15;
            int bp = br * 32 + ((l4 ^ swz(br)) * 8);
            bf16x8 bh = *reinterpret_cast<const bf16x8*>(&wb[bp]);
            bf16x8 bl_ = *reinterpret_cast<const bf16x8*>(&wb[8192 + bp]);
#pragma unroll
            for (int mi = 0; mi < 4; ++mi) {
                acc1[mi][ni] = __builtin_amdgcn_mfma_f32_16x16x32_bf16(ah[mi], bh, acc1[mi][ni], 0, 0, 0);
                acc1[mi][ni] = __builtin_amdgcn_mfma_f32_16x16x32_bf16(ah[mi], bl_, acc1[mi][ni], 0, 0, 0);
                acc1[mi][ni] = __builtin_amdgcn_mfma_f32_16x16x32_bf16(am[mi], bh, acc1[mi][ni], 0, 0, 0);
            }
        }
        __syncthreads();
        if (s < 15) { writeX(); writeW1(); __syncthreads(); }
    }

    // BN coefficients
    float scl1[8], shf1[8];
#pragma unroll
    for (int ni = 0; ni < 8; ++ni) {
        int o = wc * 128 + ni * 16 + l15;
        scl1[ni] = a.g1[o] * __frsqrt_rn(a.v1[o] + 1e-5f);
        shf1[ni] = a.b1[o] - a.m1[o] * scl1[ni];
    }
    float scl2[4], shf2[4];
#pragma unroll
    for (int ni = 0; ni < 4; ++ni) {
        int o = w * 64 + ni * 16 + l15;
        scl2[ni] = a.g2[o] * __frsqrt_rn(a.v2[o] + 1e-5f);
        shf2[ni] = a.b2[o] - a.m2[o] * scl2[ni];
    }

    auto loadW2 = [&](int s2) {
#pragma unroll
        for (int i = 0; i < 4; ++i) {
            int task = t + 256 * i;
            int row = task >> 2, c = task & 3;
            size_t off = (size_t)row * 256 + s2 * 32 + c * 8;
            rh[i] = *reinterpret_cast<const uint4*>(&a.W2h[off]);
            rl[i] = *reinterpret_cast<const uint4*>(&a.W2l[off]);
        }
    };
    auto writeW2 = [&]() {
#pragma unroll
        for (int i = 0; i < 4; ++i) {
            int task = t + 256 * i;
            int row = task >> 2, c = task & 3;
            int pos = row * 32 + ((c ^ swz(row)) * 8);
            *reinterpret_cast<uint4*>(&wb2[pos]) = rh[i];
            *reinterpret_cast<uint4*>(&wb2[8192 + pos]) = rl[i];
        }
    };

    // ---------------- phase 2: per px-quarter, q1->LDS then q2 = relu(bn2(q1 . W2))
#pragma unroll
    for (int pxq = 0; pxq < 4; ++pxq) {
        __syncthreads();                       // prior LDS users done
        loadW2(0);
        if (wr == (pxq >> 1)) {                // this wave's px-half holds the quarter
#pragma unroll
            for (int dm = 0; dm < 2; ++dm) {
                const int mi = (pxq & 1) * 2 + dm;
#pragma unroll
                for (int ni = 0; ni < 8; ++ni) {
                    int o1 = wc * 128 + ni * 16 + l15;
                    int sub = (o1 >> 5) * 32, cc = (o1 >> 3) & 3, ee = o1 & 7;
#pragma unroll
                    for (int r = 0; r < 4; ++r) {
                        int px_l = dm * 16 + l4 * 4 + r;
                        float y = fmaxf(acc1[mi][ni][r] * scl1[ni] + shf1[ni], 0.f);
                        u16 h, lo; split2(y, h, lo);
                        int pos = px_l * 256 + sub + ((cc ^ swz(px_l)) * 8) + ee;
                        q1[pos] = h;
                        q1[8192 + pos] = lo;
                    }
                }
            }
        }
        writeW2();
        __syncthreads();

        f32x4 acc2[2][4];
#pragma unroll
        for (int mi2 = 0; mi2 < 2; ++mi2)
#pragma unroll
            for (int ni = 0; ni < 4; ++ni) acc2[mi2][ni] = f32x4{0.f, 0.f, 0.f, 0.f};

        for (int s2 = 0; s2 < 8; ++s2) {       // K2 = 256 in 8 steps of 32
            if (s2 < 7) loadW2(s2 + 1);
            bf16x8 a2h[2], a2m[2];
#pragma unroll
            for (int mi2 = 0; mi2 < 2; ++mi2) {
                int ar = mi2 * 16 + l15;
                int ap = ar * 256 + s2 * 32 + ((l4 ^ swz(ar)) * 8);
                a2h[mi2] = *reinterpret_cast<const bf16x8*>(&q1[ap]);
                a2m[mi2] = *reinterpret_cast<const bf16x8*>(&q1[8192 + ap]);
            }
#pragma unroll
            for (int ni = 0; ni < 4; ++ni) {
                int br = w * 64 + ni * 16 + l15;
                int bp = br * 32 + ((l4 ^ swz(br)) * 8);
                bf16x8 b2h = *reinterpret_cast<const bf16x8*>(&wb2[bp]);
                bf16x8 b2l = *reinterpret_cast<const bf16x8*>(&wb2[8192 + bp]);
#pragma unroll
                for (int mi2 = 0; mi2 < 2; ++mi2) {
                    acc2[mi2][ni] = __builtin_amdgcn_mfma_f32_16x16x32_bf16(a2h[mi2], b2h, acc2[mi2][ni], 0, 0, 0);
                    acc2[mi2][ni] = __builtin_amdgcn_mfma_f32_16x16x32_bf16(a2h[mi2], b2l, acc2[mi2][ni], 0, 0, 0);
                    acc2[mi2][ni] = __builtin_amdgcn_mfma_f32_16x16x32_bf16(a2m[mi2], b2h, acc2[mi2][ni], 0, 0, 0);
                }
            }
            __syncthreads();
            if (s2 < 7) { writeW2(); __syncthreads(); }
        }

        // q2 epilogue: BN2+ReLU -> LDS f32 tile -> coalesced full-row stores
#pragma unroll
        for (int mi2 = 0; mi2 < 2; ++mi2)
#pragma unroll
            for (int ni = 0; ni < 4; ++ni) {
                int o2 = w * 64 + ni * 16 + l15;
#pragma unroll
                for (int r = 0; r < 4; ++r) {
                    int px_l = mi2 * 16 + l4 * 4 + r;
                    tf[px_l * 256 + o2] = fmaxf(acc2[mi2][ni][r] * scl2[ni] + shf2[ni], 0.f);
                }
            }
        __syncthreads();
#pragma unroll
        for (int j = 0; j < 8; ++j) {
            int task = j * 256 + t;
            int row = task >> 6, c4 = task & 63;
            *reinterpret_cast<float4*>(&a.q2f[(size_t)(mloc + pxq * 32 + row) * 256 + c4 * 4]) =
                *reinterpret_cast<const float4*>(&tf[row * 256 + c4 * 4]);
        }
    }
}

// ---------------------------------------------------------------- gemm_up: ctx(split planes) -> out[b][o][n] fp32
// Staging via global_load_lds (no staging VGPRs -> no spill). Pre-swizzled per-lane
// global source keeps the XOR-chunk LDS layout with a linear lane*16 destination.
struct GUArgs {
    const u16 *Ah, *Al, *Wh, *Wl;
    const float *gg, *bbv, *mmv, *vvv;
    float* Yf;
};
__global__ __launch_bounds__(256, 2) void gemm_up_kernel(GUArgs a) {
    __shared__ u16 lds[4][128 * 64];          // planes: 0=Ah 1=Al 2=Wh 3=Wl (64 KiB)
    const int t = threadIdx.x;
    const int l = t & 63;
    const int w = t >> 6;
    const int wr = w >> 1, wc = w & 1;
    const int l15 = l & 15, l4 = l >> 4;
    // bijective XCD-chunk swizzle (nwg=4096): work chunks contiguous per XCD
    const int id = blockIdx.y * 4 + blockIdx.x;
    const int wid = (id & 7) * 512 + (id >> 3);
    const int o0 = (wid & 3) * 128;
    const int m_glob = (wid >> 2) * 128;
    const int bb = m_glob >> 14;
    const int nb = m_glob & 16383;

    // per-lane pre-swizzled source offsets for DMA staging
    const int lr = l >> 3;                    // row within 8-row packet
    const int lc = (l & 7) ^ lr;              // swizzled chunk index

    f32x4 acc[4][4];
#pragma unroll
    for (int mi = 0; mi < 4; ++mi)
#pragma unroll
        for (int ni = 0; ni < 4; ++ni) acc[mi][ni] = f32x4{0.f, 0.f, 0.f, 0.f};

    for (int kt = 0; kt < 4; ++kt) {
        // stage K-tile: 16 gload16 per wave (4 per plane), wave stripes 32 rows
        const int r0 = w * 32;
#pragma unroll
        for (int i = 0; i < 4; ++i) {
            const int rl = r0 + i * 8 + lr;
            const size_t aoff = (size_t)(m_glob + rl) * 256 + kt * 64 + lc * 8;
            const size_t boff = (size_t)(o0 + rl) * 256 + kt * 64 + lc * 8;
            const int ld = (r0 + i * 8) * 64;
            gload16(a.Ah + aoff, &lds[0][ld]);
            gload16(a.Al + aoff, &lds[1][ld]);
            gload16(a.Wh + boff, &lds[2][ld]);
            gload16(a.Wl + boff, &lds[3][ld]);
        }
        __syncthreads();                       // drains vmcnt, tile ready
#pragma unroll
        for (int kk = 0; kk < 2; ++kk) {
            bf16x8 ah[4], al[4], bh[4], bl[4];
#pragma unroll
            for (int mi = 0; mi < 4; ++mi) {
                int row = wr * 64 + mi * 16 + l15;
                int idx = row * 64 + (((kk * 4 + l4) ^ (row & 7)) * 8);
                ah[mi] = *reinterpret_cast<const bf16x8*>(&lds[0][idx]);
                al[mi] = *reinterpret_cast<const bf16x8*>(&lds[1][idx]);
            }
#pragma unroll
            for (int ni = 0; ni < 4; ++ni) {
                int row = wc * 64 + ni * 16 + l15;
                int idx = row * 64 + (((kk * 4 + l4) ^ (row & 7)) * 8);
                bh[ni] = *reinterpret_cast<const bf16x8*>(&lds[2][idx]);
                bl[ni] = *reinterpret_cast<const bf16x8*>(&lds[3][idx]);
            }
#pragma unroll
            for (int mi = 0; mi < 4; ++mi)
#pragma unroll
                for (int ni = 0; ni < 4; ++ni) {
                    acc[mi][ni] = __builtin_amdgcn_mfma_f32_16x16x32_bf16(ah[mi], bh[ni], acc[mi][ni], 0, 0, 0);
                    acc[mi][ni] = __builtin_amdgcn_mfma_f32_16x16x32_bf16(ah[mi], bl[ni], acc[mi][ni], 0, 0, 0);
                    acc[mi][ni] = __builtin_amdgcn_mfma_f32_16x16x32_bf16(al[mi], bh[ni], acc[mi][ni], 0, 0, 0);
                }
        }
        __syncthreads();                       // reads done before next stage
    }

    float scl[4], shf[4];
#pragma unroll
    for (int ni = 0; ni < 4; ++ni) {
        int o = o0 + wc * 64 + ni * 16 + l15;
        scl[ni] = a.gg[o] * __frsqrt_rn(a.vvv[o] + 1e-5f);
        shf[ni] = a.bbv[o] - a.mmv[o] * scl[ni];
    }

    // transpose epilogue via LDS [64][132] f32 -> out[b][o][16384]
    float* ldsf = reinterpret_cast<float*>(&lds[0][0]);
#pragma unroll 1
    for (int pass = 0; pass < 2; ++pass) {
        __syncthreads();
#pragma unroll
        for (int nj = 0; nj < 2; ++nj) {
            int ni = pass * 2 + nj;
            int lrow = wc * 32 + nj * 16 + l15;
            int lcolb = wr * 64 + l4 * 4;
#pragma unroll
            for (int mi = 0; mi < 4; ++mi)
#pragma unroll
                for (int r = 0; r < 4; ++r) {
                    float y = fmaxf(acc[mi][ni][r] * scl[ni] + shf[ni], 0.f);
                    ldsf[lrow * 132 + lcolb + mi * 16 + r] = y;
                }
        }
        __syncthreads();
#pragma unroll
        for (int j = 0; j < 32; ++j) {
            int idx = j * 256 + t;
            int row = idx >> 7, col = idx & 127;
            int o = o0 + (row >> 5) * 64 + pass * 32 + (row & 31);
            a.Yf[((size_t)bb << 23) + (size_t)o * 16384 + nb + col] = ldsf[row * 132 + col];
        }
    }
}

// ---------------------------------------------------------------- launch
extern "C" void kernel_launch(void* const* d_in, const int* in_sizes, int n_in,
                              void* d_out, int out_size, void* d_ws, size_t ws_size,
                              hipStream_t stream) {
    const float* x     = (const float*)d_in[0];
    const float* proxy = (const float*)d_in[1];
    const float* pw1 = (const float*)d_in[2];
    const float* pg1 = (const float*)d_in[3];
    const float* pb1 = (const float*)d_in[4];
    const float* pm1 = (const float*)d_in[5];
    const float* pv1 = (const float*)d_in[6];
    const float* pw2 = (const float*)d_in[7];
    const float* pg2 = (const float*)d_in[8];
    const float* pb2 = (const float*)d_in[9];
    const float* pm2 = (const float*)d_in[10];
    const float* pv2 = (const float*)d_in[11];
    const float* ow1 = (const float*)d_in[12];
    const float* og1 = (const float*)d_in[13];
    const float* ob1 = (const float*)d_in[14];
    const float* om1 = (const float*)d_in[15];
    const float* ov1 = (const float*)d_in[16];
    const float* ow2 = (const float*)d_in[17];
    const float* og2 = (const float*)d_in[18];
    const float* ob2 = (const float*)d_in[19];
    const float* om2 = (const float*)d_in[20];
    const float* ov2 = (const float*)d_in[21];
    const float* dw  = (const float*)d_in[22];
    const float* dg  = (const float*)d_in[23];
    const float* db  = (const float*)d_in[24];
    const float* dm  = (const float*)d_in[25];
    const float* dv  = (const float*)d_in[26];
    const float* uw  = (const float*)d_in[27];
    const float* ug  = (const float*)d_in[28];
    const float* ub  = (const float*)d_in[29];
    const float* um  = (const float*)d_in[30];
    const float* uv  = (const float*)d_in[31];

    char* ws = (char*)d_ws;
    u16* wpw1h = (u16*)(ws + 0);                 // 262144 B
    u16* wpw1l = (u16*)(ws + 262144);
    u16* wpw2h = (u16*)(ws + 524288);            // 131072 B
    u16* wpw2l = (u16*)(ws + 655360);
    u16* wuwh  = (u16*)(ws + 786432);            // 262144 B
    u16* wuwl  = (u16*)(ws + 1048576);
    float* kmat = (float*)(ws + 1310720);        // 155648 B
    float* vmat = (float*)(ws + 1466368);        // 155648 B -> ends 1622016
    u16* ctxh = (u16*)(ws + 2097152);            // 67108864 B
    u16* ctxl = (u16*)(ws + 69206016);           // 67108864 B -> ends 136314880
    float* q2f = (float*)(ws + 136314880ull);    // 134217728/passes B, [chunk][256] fp32

    int passes = 1;
    while (passes < 16 && 136314880ull + 134217728ull / (size_t)passes > ws_size) passes <<= 1;

    convert_split_kernel<<<512, 256, 0, stream>>>(pw1, wpw1h, wpw1l, 131072);
    convert_split_kernel<<<256, 256, 0, stream>>>(pw2, wpw2h, wpw2l, 65536);
    convert_split_kernel<<<512, 256, 0, stream>>>(uw,  wuwh,  wuwl,  131072);

    KVArgs ka{proxy, ow1, og1, ob1, om1, ov1, ow2, og2, ob2, om2, ov2,
              dw, dg, db, dm, dv, kmat, vmat};
    kv_kernel<<<8, 256, 0, stream>>>(ka);

    const int mb = 1024 / passes;                // 128-px blocks per pass
    for (int p = 0; p < passes; ++p) {
        const int m_off = p * mb * 128;
        F12Args fa{x, wpw1h, wpw1l, wpw2h, wpw2l,
                   pg1, pb1, pm1, pv1, pg2, pb2, pm2, pv2, q2f, m_off};
        fused12_kernel<<<mb, 256, 0, stream>>>(fa);
        AttnArgs aa{q2f, kmat, vmat, ctxh, ctxl, (long long)m_off};
        attn_kernel<<<mb / 2, 256, 0, stream>>>(aa);
    }

    // gemm_up: ctx -> out[b][o][n] fp32, K=256, COUT=512
    GUArgs ga{ctxh, ctxl, wuwh, wuwl, ug, ub, um, uv, (float*)d_out};
    gemm_up_kernel<<<dim3(4, 1024), 256, 0, stream>>>(ga);
}